// Round 1
// baseline (192.740 us; speedup 1.0000x reference)
//
#include <hip/hip_runtime.h>

typedef __attribute__((ext_vector_type(8))) short bf16x8;
typedef __attribute__((ext_vector_type(4))) short bf16x4;
typedef __attribute__((ext_vector_type(4))) float f32x4;

__device__ __forceinline__ unsigned short f2bf(float f) {
    union { float f; unsigned int u; } v; v.f = f;
    unsigned int r = v.u + 0x7fffu + ((v.u >> 16) & 1u);
    return (unsigned short)(r >> 16);
}

// ---------------------------------------------------------------------------
// Kernel 1: grouped 1x1 conv.  x[h][i][n] = sum_j W[g][i][j] p[h][j][n] + b
// Writes xqT [h][n][i] (bf16, i contiguous)  -> QK MFMA operands
//        xv  [h][i][n] (bf16, n contiguous)  -> PV A-operand (V = elu(x))
// ---------------------------------------------------------------------------
__global__ __launch_bounds__(256) void conv_kernel(
    const float* __restrict__ points, const float* __restrict__ conv_w,
    const float* __restrict__ conv_b,
    unsigned short* __restrict__ xqT, unsigned short* __restrict__ xv)
{
    __shared__ float w[1024];
    const int h  = blockIdx.x >> 4;   // 16 heads
    const int nc = blockIdx.x & 15;   // 16 n-chunks of 256
    const int g  = h & 7;
    const int tid = threadIdx.x;
    const float* wg = conv_w + g * 1024;
    for (int k = tid; k < 1024; k += 256) w[k] = wg[k];
    __syncthreads();
    const int n = nc * 256 + tid;
    const float* p = points + (size_t)h * 32 * 4096 + n;  // (b*256+g*32+j) == h*32+j
    float pv[32];
#pragma unroll
    for (int j = 0; j < 32; ++j) pv[j] = p[(size_t)j * 4096];
    float out[32];
#pragma unroll
    for (int i = 0; i < 32; ++i) {
        float acc = conv_b[g * 32 + i];
#pragma unroll
        for (int j = 0; j < 32; ++j) acc += w[i * 32 + j] * pv[j];
        out[i] = acc;
    }
    unsigned short tq[32];
#pragma unroll
    for (int i = 0; i < 32; ++i) tq[i] = f2bf(out[i]);
    bf16x8* dst = (bf16x8*)(xqT + ((size_t)h * 4096 + n) * 32);
#pragma unroll
    for (int t = 0; t < 4; ++t) dst[t] = ((bf16x8*)tq)[t];
#pragma unroll
    for (int i = 0; i < 32; ++i) {
        float x = out[i];
        float e = x > 0.f ? x : (__expf(x) - 1.f);   // elu
        xv[((size_t)h * 32 + i) * 4096 + n] = f2bf(e);
    }
}

// ---------------------------------------------------------------------------
// Kernel 2: flash attention (no-max softmax, valid since |scores| << 88).
//   S[n][m] = sum_i K^T[n][i] Q[i][m]        (one 16x16x32 MFMA, K=32=headdim)
//   p = exp(S*scale); l[m] += sum_n p; O[i][m] += sum_n V[i][n] p[n][m]
// Block: 4 waves x 16 queries = 64-query tile; K-loop in 64-key chunks.
// Output: channel shuffle (ch = i*8+g) + residual, fp32 -> d_out.
// ---------------------------------------------------------------------------
#define KSTR 40   // 32 + 8 pad (elems)  -> row 80B, 16B aligned, 2-way banks
#define VSTR 72   // 64 + 8 pad          -> row 144B
#define PSTR 72   // 64 + 8 pad          -> row 144B

__global__ __launch_bounds__(256) void attn_kernel(
    const unsigned short* __restrict__ xqT,
    const unsigned short* __restrict__ xv,
    const float* __restrict__ points,
    float* __restrict__ z)
{
    __shared__ unsigned short Kt[64 * KSTR];   // [n][i]
    __shared__ unsigned short Vt[32 * VSTR];   // [i][n]
    __shared__ unsigned short Pl[4][16 * PSTR];// per-wave [m][n]

    const int qt = blockIdx.x;
    const int h  = blockIdx.y;
    const int b = h >> 3, g = h & 7;
    const int tid = threadIdx.x;
    const int wv = tid >> 6, lane = tid & 63;
    const int quad = lane >> 4, l15 = lane & 15;

    const int m = qt * 64 + wv * 16 + l15;   // this lane's query column

    const unsigned short* kbase = xqT + (size_t)h * 4096 * 32;
    const unsigned short* vbase = xv  + (size_t)h * 32 * 4096;

    // Q fragment (B-operand): B[k=i][col=m], lane: col=l15, k=quad*8+j
    const bf16x8 qfrag = *(const bf16x8*)(kbase + (size_t)m * 32 + quad * 8);

    f32x4 acc0 = {0.f, 0.f, 0.f, 0.f};   // O rows i = 0..15
    f32x4 acc1 = {0.f, 0.f, 0.f, 0.f};   // O rows i = 16..31
    float lsum = 0.f;

    const int kr = tid >> 2, kc = (tid & 3) * 8;   // K staging: [n][i]
    const int vi = tid >> 3, vn = (tid & 7) * 8;   // V staging: [i][n]

    unsigned short* pw = &Pl[wv][0];

    for (int n0 = 0; n0 < 4096; n0 += 64) {
        __syncthreads();
        *(bf16x8*)(Kt + kr * KSTR + kc) =
            *(const bf16x8*)(kbase + (size_t)(n0 + kr) * 32 + kc);
        *(bf16x8*)(Vt + vi * VSTR + vn) =
            *(const bf16x8*)(vbase + (size_t)vi * 4096 + n0 + vn);
        __syncthreads();

#pragma unroll
        for (int s = 0; s < 4; ++s) {
            // A-operand K^T: A[r=n][k=i], lane: r=l15 -> n = s*16+l15
            bf16x8 kf = *(const bf16x8*)(Kt + (s * 16 + l15) * KSTR + quad * 8);
            f32x4 sc = __builtin_amdgcn_mfma_f32_16x16x32_bf16(
                kf, qfrag, (f32x4){0.f, 0.f, 0.f, 0.f}, 0, 0, 0);
            // C/D: col=m=l15, row n = s*16 + quad*4 + r
            bf16x4 pk;
#pragma unroll
            for (int r = 0; r < 4; ++r) {
                float e = __expf(sc[r] * 0.17677669529663687f);
                lsum += e;
                pk[r] = (short)f2bf(e);
            }
            *(bf16x4*)(pw + l15 * PSTR + s * 16 + quad * 4) = pk;
        }
#pragma unroll
        for (int ng = 0; ng < 2; ++ng) {
            // B-operand P: B[k=n][col=m], lane: col=l15, k = ng*32+quad*8+j
            bf16x8 pf = *(const bf16x8*)(pw + l15 * PSTR + ng * 32 + quad * 8);
            // A-operand V: A[r=i][k=n]
            bf16x8 v0 = *(const bf16x8*)(Vt + l15 * VSTR + ng * 32 + quad * 8);
            bf16x8 v1 = *(const bf16x8*)(Vt + (16 + l15) * VSTR + ng * 32 + quad * 8);
            acc0 = __builtin_amdgcn_mfma_f32_16x16x32_bf16(v0, pf, acc0, 0, 0, 0);
            acc1 = __builtin_amdgcn_mfma_f32_16x16x32_bf16(v1, pf, acc1, 0, 0, 0);
        }
    }

    // denominator: sum partial l over the 4 quads sharing column m
    lsum += __shfl_xor(lsum, 16, 64);
    lsum += __shfl_xor(lsum, 32, 64);
    const float inv = 1.f / lsum;

    const float* pb = points + (size_t)b * 256 * 4096;
    float* zb = z + (size_t)b * 256 * 4096;
#pragma unroll
    for (int half = 0; half < 2; ++half) {
        f32x4 a = half ? acc1 : acc0;
#pragma unroll
        for (int r = 0; r < 4; ++r) {
            int i = half * 16 + quad * 4 + r;        // C/D row mapping
            size_t off = (size_t)(i * 8 + g) * 4096 + m;  // channel shuffle
            zb[off] = a[r] * inv + pb[off];          // + identity
        }
    }
}

// ---------------------------------------------------------------------------
// Kernel 3: GroupNorm stats. 64 blocks = (b, gn_group); 8 ch x 4096 = 32768 el
// ---------------------------------------------------------------------------
__global__ __launch_bounds__(256) void gn_stats(const float* __restrict__ z,
                                                float* __restrict__ stats)
{
    const int blk = blockIdx.x;
    const int tid = threadIdx.x;
    const float4* p = (const float4*)(z + (size_t)blk * 32768);
    float s = 0.f, ss = 0.f;
    for (int k = tid; k < 8192; k += 256) {
        float4 v = p[k];
        s  += v.x + v.y + v.z + v.w;
        ss += v.x * v.x + v.y * v.y + v.z * v.z + v.w * v.w;
    }
#pragma unroll
    for (int off = 32; off > 0; off >>= 1) {
        s  += __shfl_down(s, off, 64);
        ss += __shfl_down(ss, off, 64);
    }
    __shared__ float red[8];
    const int w = tid >> 6;
    if ((tid & 63) == 0) { red[w * 2] = s; red[w * 2 + 1] = ss; }
    __syncthreads();
    if (tid == 0) {
        s  = red[0] + red[2] + red[4] + red[6];
        ss = red[1] + red[3] + red[5] + red[7];
        float mean = s * (1.f / 32768.f);
        float var  = ss * (1.f / 32768.f) - mean * mean;
        stats[blk * 2]     = mean;
        stats[blk * 2 + 1] = rsqrtf(var + 1e-5f);
    }
}

// ---------------------------------------------------------------------------
// Kernel 4: GroupNorm apply, in place on d_out.
// ---------------------------------------------------------------------------
__global__ __launch_bounds__(256) void gn_apply(float* __restrict__ z,
                                                const float* __restrict__ stats,
                                                const float* __restrict__ gw,
                                                const float* __restrict__ gb)
{
    const int idx = blockIdx.x * 256 + threadIdx.x;  // float4 index
    float4* p = (float4*)z;
    float4 v = p[idx];
    const int chg = idx >> 10;       // global channel b*256+ch (4096/4 per ch)
    const int blk = chg >> 3;        // stats slot = b*32 + ch/8
    const int ch  = chg & 255;
    const float mean = stats[blk * 2], rstd = stats[blk * 2 + 1];
    const float w  = gw[ch] * rstd;
    const float bb = gb[ch] - mean * w;
    v.x = v.x * w + bb; v.y = v.y * w + bb;
    v.z = v.z * w + bb; v.w = v.w * w + bb;
    p[idx] = v;
}

extern "C" void kernel_launch(void* const* d_in, const int* in_sizes, int n_in,
                              void* d_out, int out_size, void* d_ws, size_t ws_size,
                              hipStream_t stream)
{
    const float* points = (const float*)d_in[0];
    const float* conv_w = (const float*)d_in[1];
    const float* conv_b = (const float*)d_in[2];
    const float* gn_w   = (const float*)d_in[3];
    const float* gn_b   = (const float*)d_in[4];
    float* out = (float*)d_out;
    char* ws = (char*)d_ws;
    unsigned short* xqT = (unsigned short*)ws;                            // 4 MB
    unsigned short* xv  = (unsigned short*)(ws + (size_t)4 * 1024 * 1024); // 4 MB
    float* stats = (float*)(ws + (size_t)8 * 1024 * 1024);                // 512 B

    conv_kernel<<<256, 256, 0, stream>>>(points, conv_w, conv_b, xqT, xv);
    attn_kernel<<<dim3(64, 16), 256, 0, stream>>>(xqT, xv, points, out);
    gn_stats<<<64, 256, 0, stream>>>(out, stats);
    gn_apply<<<2048, 256, 0, stream>>>(out, stats, gn_w, gn_b);
}